// Round 1
// baseline (173.385 us; speedup 1.0000x reference)
//
#include <hip/hip_runtime.h>
#include <math.h>

// DifferentiableSimulator: v' = alpha*v + beta*a ; x' = x + DT*v'
// alpha = 1 - fric*DT/m_safe, beta = DT/m_safe, m_safe = |mass|+0.001
// Parallelized as reduce-then-scan over affine maps (A,B,C,D):
//   v_out = A*v_in + B ; x_out = x_in + C*v_in + D
// compose(first=(A1,B1,C1,D1), then=(A2,B2,C2,D2)) =
//   (A2*A1, A2*B1+B2, C1+C2*A1, D1+C2*B1+D2)
// A and C for a length-n uniform segment are analytic:
//   A_n = alpha^n ; C_n = DT*alpha*(1-alpha^n)/(1-alpha)

#define TPB 256
#define SEG 32
#define STEPS_PER_BLOCK (TPB * SEG)  // 8192

__device__ __forceinline__ double ipow_d(double a, int n) {
    double r = 1.0, b = a;
    while (n) { if (n & 1) r *= b; b *= b; n >>= 1; }
    return r;
}

__device__ __forceinline__ double cgeom(double alpha, double An, int n) {
    const double DTd = (double)0.01f;
    double den = 1.0 - alpha;
    if (fabs(den) < 1e-12) return DTd * (double)n;  // alpha ~ 1 limit
    return DTd * alpha * (1.0 - An) / den;
}

// ---------------- Kernel 1: per-thread segment aggregates + intra-block scan
__global__ __launch_bounds__(TPB) void k1_reduce(
        const float* __restrict__ act,
        const float* __restrict__ mp,
        const float* __restrict__ fp,
        float4* __restrict__ thrPre,   // [nThreads] exclusive prefix map (A,B,C,D) within block
        float2* __restrict__ blkAgg)   // [nBlocks]  block aggregate (B,D)
{
    __shared__ double sA[TPB], sB[TPB], sC[TPB], sD[TPB];
    const int t = threadIdx.x;
    const int g = blockIdx.x * TPB + t;

    const float m_safe = fabsf(mp[0]) + 0.001f;
    const float fric   = fp[0];
    const float DTf    = 0.01f;
    const float beta   = DTf / m_safe;
    const float alpha  = 1.0f - fric * beta;

    // simulate 32 steps from (x=0, v=0): result is (D, B) of this thread's map
    const float4* ap = (const float4*)(act + (size_t)g * SEG);
    float v = 0.0f, x = 0.0f;
#pragma unroll
    for (int i = 0; i < SEG / 4; ++i) {
        float4 a = ap[i];
        v = fmaf(alpha, v, beta * a.x); x = fmaf(v, DTf, x);
        v = fmaf(alpha, v, beta * a.y); x = fmaf(v, DTf, x);
        v = fmaf(alpha, v, beta * a.z); x = fmaf(v, DTf, x);
        v = fmaf(alpha, v, beta * a.w); x = fmaf(v, DTf, x);
    }

    const double ad  = 1.0 - (double)fric * ((double)0.01f) / (double)m_safe;
    const double A32 = ipow_d(ad, SEG);
    const double C32 = cgeom(ad, A32, SEG);

    sA[t] = A32; sB[t] = (double)v; sC[t] = C32; sD[t] = (double)x;
    __syncthreads();

    // Hillis-Steele inclusive scan over the block's 256 thread maps (fp64)
    for (int d = 1; d < TPB; d <<= 1) {
        double a1, b1, c1, d1, a2, b2, c2, d2;
        const bool p = (t >= d);
        if (p) {
            a1 = sA[t - d]; b1 = sB[t - d]; c1 = sC[t - d]; d1 = sD[t - d];
            a2 = sA[t];     b2 = sB[t];     c2 = sC[t];     d2 = sD[t];
        }
        __syncthreads();
        if (p) {
            sA[t] = a2 * a1;
            sB[t] = fma(a2, b1, b2);
            sC[t] = fma(c2, a1, c1);
            sD[t] = fma(c2, b1, d1 + d2);
        }
        __syncthreads();
    }

    // exclusive prefix for this thread (identity for t==0)
    float4 pre;
    if (t == 0) pre = make_float4(1.0f, 0.0f, 0.0f, 0.0f);
    else        pre = make_float4((float)sA[t - 1], (float)sB[t - 1],
                                  (float)sC[t - 1], (float)sD[t - 1]);
    thrPre[g] = pre;
    if (t == TPB - 1)
        blkAgg[blockIdx.x] = make_float2((float)sB[TPB - 1], (float)sD[TPB - 1]);
}

// ---------------- Kernel 2: scan block aggregates (single block), apply init
__global__ __launch_bounds__(1024) void k2_scan(
        const float2* __restrict__ blkAgg,
        float2* __restrict__ blkPre,   // [nBlocks] (v_in, x_in) at each block start
        const float* __restrict__ init,
        const float* __restrict__ mp,
        const float* __restrict__ fp,
        int nBlocks)
{
    __shared__ double sA[1024], sB[1024], sC[1024], sD[1024];
    const int t = threadIdx.x;

    const float  m_safe = fabsf(mp[0]) + 0.001f;
    const double ad  = 1.0 - (double)fp[0] * ((double)0.01f) / (double)m_safe;
    const double Ab  = ipow_d(ad, STEPS_PER_BLOCK);
    const double Cb  = cgeom(ad, Ab, STEPS_PER_BLOCK);

    if (t < nBlocks) {
        float2 bd = blkAgg[t];
        sA[t] = Ab; sB[t] = (double)bd.x; sC[t] = Cb; sD[t] = (double)bd.y;
    } else {
        sA[t] = 1.0; sB[t] = 0.0; sC[t] = 0.0; sD[t] = 0.0;  // identity
    }
    __syncthreads();

    for (int d = 1; d < 1024; d <<= 1) {
        double a1, b1, c1, d1, a2, b2, c2, d2;
        const bool p = (t >= d);
        if (p) {
            a1 = sA[t - d]; b1 = sB[t - d]; c1 = sC[t - d]; d1 = sD[t - d];
            a2 = sA[t];     b2 = sB[t];     c2 = sC[t];     d2 = sD[t];
        }
        __syncthreads();
        if (p) {
            sA[t] = a2 * a1;
            sB[t] = fma(a2, b1, b2);
            sC[t] = fma(c2, a1, c1);
            sD[t] = fma(c2, b1, d1 + d2);
        }
        __syncthreads();
    }

    if (t < nBlocks) {
        const double v0 = (double)init[1];
        const double x0 = (double)init[0];
        double vin, xin;
        if (t == 0) { vin = v0; xin = x0; }
        else {
            vin = fma(sA[t - 1], v0, sB[t - 1]);
            xin = x0 + sC[t - 1] * v0 + sD[t - 1];
        }
        blkPre[t] = make_float2((float)vin, (float)xin);
    }
}

// ---------------- Kernel 3: final pass — re-simulate with true entry state
__global__ __launch_bounds__(TPB) void k3_emit(
        const float* __restrict__ act,
        const float4* __restrict__ thrPre,
        const float2* __restrict__ blkPre,
        const float* __restrict__ init,
        const float* __restrict__ mp,
        const float* __restrict__ fp,
        float2* __restrict__ out2)
{
    const int t = threadIdx.x;
    const int g = blockIdx.x * TPB + t;

    const float m_safe = fabsf(mp[0]) + 0.001f;
    const float fric   = fp[0];
    const float DTf    = 0.01f;
    const float beta   = DTf / m_safe;
    const float alpha  = 1.0f - fric * beta;

    const float2 bp = blkPre[blockIdx.x];   // (v_in, x_in) at block start
    const float4 pm = thrPre[g];            // (A,B,C,D) exclusive prefix in block
    float v = fmaf(pm.x, bp.x, pm.y);
    float x = bp.y + pm.z * bp.x + pm.w;

    if (g == 0) out2[0] = make_float2(init[0], init[1]);  // row 0 = initial state

    const float4* ap = (const float4*)(act + (size_t)g * SEG);
    float2* op = out2 + (size_t)g * SEG + 1;
#pragma unroll
    for (int i = 0; i < SEG / 4; ++i) {
        float4 a = ap[i];
        v = fmaf(alpha, v, beta * a.x); x = fmaf(v, DTf, x); op[4 * i + 0] = make_float2(x, v);
        v = fmaf(alpha, v, beta * a.y); x = fmaf(v, DTf, x); op[4 * i + 1] = make_float2(x, v);
        v = fmaf(alpha, v, beta * a.z); x = fmaf(v, DTf, x); op[4 * i + 2] = make_float2(x, v);
        v = fmaf(alpha, v, beta * a.w); x = fmaf(v, DTf, x); op[4 * i + 3] = make_float2(x, v);
    }
}

extern "C" void kernel_launch(void* const* d_in, const int* in_sizes, int n_in,
                              void* d_out, int out_size, void* d_ws, size_t ws_size,
                              hipStream_t stream) {
    const float* init    = (const float*)d_in[0];   // (1,2): [x0, v0]
    const float* actions = (const float*)d_in[1];   // (T,1)
    const float* mass    = (const float*)d_in[2];
    const float* fric    = (const float*)d_in[3];

    const int T = in_sizes[1];                      // 8388608
    const int nThreads = T / SEG;                   // 262144
    const int nBlocks  = T / STEPS_PER_BLOCK;       // 1024 (<= 1024 required by k2)

    // workspace layout
    float4* thrPre = (float4*)d_ws;                                  // 4 MB
    float2* blkAgg = (float2*)((char*)d_ws + (size_t)nThreads * 16); // 8 KB
    float2* blkPre = blkAgg + nBlocks;                               // 8 KB

    k1_reduce<<<nBlocks, TPB, 0, stream>>>(actions, mass, fric, thrPre, blkAgg);
    k2_scan<<<1, 1024, 0, stream>>>(blkAgg, blkPre, init, mass, fric, nBlocks);
    k3_emit<<<nBlocks, TPB, 0, stream>>>(actions, thrPre, blkPre, init, mass, fric,
                                         (float2*)d_out);
}

// Round 3
// 114.800 us; speedup vs baseline: 1.5103x; 1.5103x over previous
//
#include <hip/hip_runtime.h>
#include <math.h>

// DifferentiableSimulator: v' = alpha*v + beta*a ; x' = x + DT*v'
// alpha = 1 - fric*DT/m_safe, beta = DT/m_safe, m_safe = |mass|+0.001
// Parallelized as reduce-then-scan over affine maps (A,B,C,D):
//   v_out = A*v_in + B ; x_out = x_in + C*v_in + D
// compose(first=(A1,B1,C1,D1), then=(A2,B2,C2,D2)) =
//   (A2*A1, A2*B1+B2, C1+C2*A1, D1+C2*B1+D2)
// A and C for a length-n uniform segment are analytic:
//   A_n = alpha^n ; C_n = DT*alpha*(1-alpha^n)/(1-alpha)
//
// R3: k3 stages the FULL 32-entry thread segment in LDS (64 KB, XOR-swizzled
// float4 layout, conflict-free b128 ops), and shifts each thread's staged
// window to [g*32, g*32+32) = entry state + 31 post-states. Block region is
// then exactly out2[b*8192 .. +8191]: contiguous AND 64B-aligned float4
// flush (R1: 4.6x write amplification from 8B scattered stores; R2: half-
// staging flushed an interleaved entry set as if contiguous -> wrong output).

#define TPB 256
#define SEG 32
#define STEPS_PER_BLOCK (TPB * SEG)  // 8192

__device__ __forceinline__ double ipow_d(double a, int n) {
    double r = 1.0, b = a;
    while (n) { if (n & 1) r *= b; b *= b; n >>= 1; }
    return r;
}

__device__ __forceinline__ double cgeom(double alpha, double An, int n) {
    const double DTd = (double)0.01f;
    double den = 1.0 - alpha;
    if (fabs(den) < 1e-12) return DTd * (double)n;  // alpha ~ 1 limit
    return DTd * alpha * (1.0 - An) / den;
}

// ---------------- Kernel 1: per-thread segment aggregates + intra-block scan
__global__ __launch_bounds__(TPB) void k1_reduce(
        const float* __restrict__ act,
        const float* __restrict__ mp,
        const float* __restrict__ fp,
        float4* __restrict__ thrPre,   // [nThreads] exclusive prefix map (A,B,C,D) within block
        float2* __restrict__ blkAgg)   // [nBlocks]  block aggregate (B,D)
{
    __shared__ double sA[TPB], sB[TPB], sC[TPB], sD[TPB];
    const int t = threadIdx.x;
    const int g = blockIdx.x * TPB + t;

    const float m_safe = fabsf(mp[0]) + 0.001f;
    const float fric   = fp[0];
    const float DTf    = 0.01f;
    const float beta   = DTf / m_safe;
    const float alpha  = 1.0f - fric * beta;

    // simulate 32 steps from (x=0, v=0): result is (D, B) of this thread's map
    const float4* ap = (const float4*)(act + (size_t)g * SEG);
    float v = 0.0f, x = 0.0f;
#pragma unroll
    for (int i = 0; i < SEG / 4; ++i) {
        float4 a = ap[i];
        v = fmaf(alpha, v, beta * a.x); x = fmaf(v, DTf, x);
        v = fmaf(alpha, v, beta * a.y); x = fmaf(v, DTf, x);
        v = fmaf(alpha, v, beta * a.z); x = fmaf(v, DTf, x);
        v = fmaf(alpha, v, beta * a.w); x = fmaf(v, DTf, x);
    }

    const double ad  = 1.0 - (double)fric * ((double)0.01f) / (double)m_safe;
    const double A32 = ipow_d(ad, SEG);
    const double C32 = cgeom(ad, A32, SEG);

    sA[t] = A32; sB[t] = (double)v; sC[t] = C32; sD[t] = (double)x;
    __syncthreads();

    // Hillis-Steele inclusive scan over the block's 256 thread maps (fp64)
    for (int d = 1; d < TPB; d <<= 1) {
        double a1, b1, c1, d1, a2, b2, c2, d2;
        const bool p = (t >= d);
        if (p) {
            a1 = sA[t - d]; b1 = sB[t - d]; c1 = sC[t - d]; d1 = sD[t - d];
            a2 = sA[t];     b2 = sB[t];     c2 = sC[t];     d2 = sD[t];
        }
        __syncthreads();
        if (p) {
            sA[t] = a2 * a1;
            sB[t] = fma(a2, b1, b2);
            sC[t] = fma(c2, a1, c1);
            sD[t] = fma(c2, b1, d1 + d2);
        }
        __syncthreads();
    }

    // exclusive prefix for this thread (identity for t==0)
    float4 pre;
    if (t == 0) pre = make_float4(1.0f, 0.0f, 0.0f, 0.0f);
    else        pre = make_float4((float)sA[t - 1], (float)sB[t - 1],
                                  (float)sC[t - 1], (float)sD[t - 1]);
    thrPre[g] = pre;
    if (t == TPB - 1)
        blkAgg[blockIdx.x] = make_float2((float)sB[TPB - 1], (float)sD[TPB - 1]);
}

// ---------------- Kernel 2: scan block aggregates (single block), apply init
__global__ __launch_bounds__(1024) void k2_scan(
        const float2* __restrict__ blkAgg,
        float2* __restrict__ blkPre,   // [nBlocks] (v_in, x_in) at each block start
        const float* __restrict__ init,
        const float* __restrict__ mp,
        const float* __restrict__ fp,
        int nBlocks)
{
    __shared__ double sA[1024], sB[1024], sC[1024], sD[1024];
    const int t = threadIdx.x;

    const float  m_safe = fabsf(mp[0]) + 0.001f;
    const double ad  = 1.0 - (double)fp[0] * ((double)0.01f) / (double)m_safe;
    const double Ab  = ipow_d(ad, STEPS_PER_BLOCK);
    const double Cb  = cgeom(ad, Ab, STEPS_PER_BLOCK);

    if (t < nBlocks) {
        float2 bd = blkAgg[t];
        sA[t] = Ab; sB[t] = (double)bd.x; sC[t] = Cb; sD[t] = (double)bd.y;
    } else {
        sA[t] = 1.0; sB[t] = 0.0; sC[t] = 0.0; sD[t] = 0.0;  // identity
    }
    __syncthreads();

    for (int d = 1; d < 1024; d <<= 1) {
        double a1, b1, c1, d1, a2, b2, c2, d2;
        const bool p = (t >= d);
        if (p) {
            a1 = sA[t - d]; b1 = sB[t - d]; c1 = sC[t - d]; d1 = sD[t - d];
            a2 = sA[t];     b2 = sB[t];     c2 = sC[t];     d2 = sD[t];
        }
        __syncthreads();
        if (p) {
            sA[t] = a2 * a1;
            sB[t] = fma(a2, b1, b2);
            sC[t] = fma(c2, a1, c1);
            sD[t] = fma(c2, b1, d1 + d2);
        }
        __syncthreads();
    }

    if (t < nBlocks) {
        const double v0 = (double)init[1];
        const double x0 = (double)init[0];
        double vin, xin;
        if (t == 0) { vin = v0; xin = x0; }
        else {
            vin = fma(sA[t - 1], v0, sB[t - 1]);
            xin = x0 + sC[t - 1] * v0 + sD[t - 1];
        }
        blkPre[t] = make_float2((float)vin, (float)xin);
    }
}

// ---------------- Kernel 3: re-simulate; stage [g*32, g*32+32) in swizzled LDS;
// ---------------- flush block-contiguous, 64B-aligned, full float4.
__global__ __launch_bounds__(TPB) void k3_emit(
        const float* __restrict__ act,
        const float4* __restrict__ thrPre,
        const float2* __restrict__ blkPre,
        const float* __restrict__ mp,
        const float* __restrict__ fp,
        float2* __restrict__ out2,
        int nThreads)
{
    // 256 threads x 16 float4 (= 32 float2 states) = 65536 B exactly.
    // XOR swizzle on the float4 index breaks bank aliasing without padding.
    __shared__ float4 sOut[TPB * 16];
    const int t = threadIdx.x;
    const int b = blockIdx.x;
    const int g = b * TPB + t;

    const float m_safe = fabsf(mp[0]) + 0.001f;
    const float fric   = fp[0];
    const float DTf    = 0.01f;
    const float beta   = DTf / m_safe;
    const float alpha  = 1.0f - fric * beta;

    const float2 bp = blkPre[b];            // (v_in, x_in) at block start
    const float4 pm = thrPre[g];            // (A,B,C,D) exclusive prefix in block
    float v = fmaf(pm.x, bp.x, pm.y);       // entry state = state after g*32 actions
    float x = bp.y + pm.z * bp.x + pm.w;

    const float4* ap = (const float4*)(act + (size_t)g * SEG);
    float4* so = &sOut[t * 16];
    const int sw = t & 15;

    // stage entries [g*32 .. g*32+31]: entry state + states after actions 0..30
#pragma unroll
    for (int q = 0; q < SEG / 4; ++q) {
        float4 a = ap[q];
        float4 e0, e1;
        e0.x = x; e0.y = v;                                   // state after 4q actions
        v = fmaf(alpha, v, beta * a.x); x = fmaf(v, DTf, x);
        e0.z = x; e0.w = v;                                   // after 4q+1
        v = fmaf(alpha, v, beta * a.y); x = fmaf(v, DTf, x);
        e1.x = x; e1.y = v;                                   // after 4q+2
        v = fmaf(alpha, v, beta * a.z); x = fmaf(v, DTf, x);
        e1.z = x; e1.w = v;                                   // after 4q+3
        v = fmaf(alpha, v, beta * a.w); x = fmaf(v, DTf, x);  // after 4q+4 (next iter / final)
        so[(2 * q) ^ sw]     = e0;
        so[(2 * q + 1) ^ sw] = e1;
    }
    // (x,v) now = state after all 32 actions; only the globally-last thread emits it
    if (g == nThreads - 1)
        out2[(size_t)nThreads * SEG] = make_float2(x, v);

    __syncthreads();

    // flush: block covers out2[b*8192 .. b*8192+8191] == float4 [b*4096 .. +4095]
    float4* o4 = (float4*)out2 + (size_t)b * (STEPS_PER_BLOCK / 2);
#pragma unroll
    for (int it = 0; it < 16; ++it) {
        const int j = t + it * TPB;                 // linear float4 index in block
        const int src = (j & ~15) | ((j & 15) ^ ((j >> 4) & 15));
        o4[j] = sOut[src];
    }
}

extern "C" void kernel_launch(void* const* d_in, const int* in_sizes, int n_in,
                              void* d_out, int out_size, void* d_ws, size_t ws_size,
                              hipStream_t stream) {
    const float* init    = (const float*)d_in[0];   // (1,2): [x0, v0]
    const float* actions = (const float*)d_in[1];   // (T,1)
    const float* mass    = (const float*)d_in[2];
    const float* fric    = (const float*)d_in[3];

    const int T = in_sizes[1];                      // 8388608
    const int nThreads = T / SEG;                   // 262144
    const int nBlocks  = T / STEPS_PER_BLOCK;       // 1024 (<= 1024 required by k2)

    // workspace layout
    float4* thrPre = (float4*)d_ws;                                  // 4 MB
    float2* blkAgg = (float2*)((char*)d_ws + (size_t)nThreads * 16); // 8 KB
    float2* blkPre = blkAgg + nBlocks;                               // 8 KB

    k1_reduce<<<nBlocks, TPB, 0, stream>>>(actions, mass, fric, thrPre, blkAgg);
    k2_scan<<<1, 1024, 0, stream>>>(blkAgg, blkPre, init, mass, fric, nBlocks);
    k3_emit<<<nBlocks, TPB, 0, stream>>>(actions, thrPre, blkPre, mass, fric,
                                         (float2*)d_out, nThreads);
}